// Round 1
// baseline (271.024 us; speedup 1.0000x reference)
//
#include <hip/hip_runtime.h>
#include <stdint.h>

typedef unsigned short u16;
typedef __bf16 bf16x8 __attribute__((ext_vector_type(8)));
typedef float f32x16 __attribute__((ext_vector_type(16)));
typedef u16 u16x8 __attribute__((ext_vector_type(8)));

__device__ __forceinline__ u16 f2bf(float f) {
  uint32_t u = __float_as_uint(f);
  u += 0x7fffu + ((u >> 16) & 1u);   // round-to-nearest-even
  return (u16)(u >> 16);
}

// ---------------------------------------------------------------------------
// build_lr: blocks 0..15 build L4[A_L(128)][B_L(128)][r4(16)] (fp32, 1 MiB),
//           block 16 builds R[A_R(16)][B_R(16)][r4(16)] (fp32, 16 KiB).
// Digit order: A = a0 most significant ... a8 least. Core 7 is bond-swapped.
// ---------------------------------------------------------------------------
__global__ __launch_bounds__(256) void build_lr_kernel(
    const float* __restrict__ p0, const float* __restrict__ p1,
    const float* __restrict__ p2, const float* __restrict__ p3,
    const float* __restrict__ p4, const float* __restrict__ p5,
    const float* __restrict__ p6, const float* __restrict__ p7,
    const float* __restrict__ p8, float* __restrict__ L4, float* __restrict__ R) {
  __shared__ float sA[16384];
  __shared__ float sB[4096];
  const int tid = threadIdx.x;
  if (blockIdx.x < 16) {
    for (int i = tid; i < 1024; i += 256) sA[i] = p0[i];
    __syncthreads();
    // step1: sA[8][8][16] x p1 -> sB[16][16][16]
    for (int i = tid; i < 4096; i += 256) {
      int r = i & 15, t = i >> 4;
      int Bb = t & 15, Aa = t >> 4;
      int a = Aa & 1, A = Aa >> 1, b = Bb & 1, B = Bb >> 1;
      const float* srow = sA + (A * 8 + B) * 16;
      const float* g = p1 + ((a * 2 + b) * 16) * 16 + r;
      float s = 0.f;
#pragma unroll
      for (int l = 0; l < 16; l++) s += srow[l] * g[l * 16];
      sB[i] = s;
    }
    __syncthreads();
    // step2: sB[16][16][16] x p2 -> sA[32][32][16]
    for (int i = tid; i < 16384; i += 256) {
      int r = i & 15, t = i >> 4;
      int Bb = t & 31, Aa = t >> 5;
      int a = Aa & 1, A = Aa >> 1, b = Bb & 1, B = Bb >> 1;
      const float* srow = sB + (A * 16 + B) * 16;
      const float* g = p2 + ((a * 2 + b) * 16) * 16 + r;
      float s = 0.f;
#pragma unroll
      for (int l = 0; l < 16; l++) s += srow[l] * g[l * 16];
      sA[i] = s;
    }
    __syncthreads();
    // fused steps 3+4
    int gi = blockIdx.x * 256 + tid;  // 0..4095
    int b3 = gi & 1, a3 = (gi >> 1) & 1;
    int B2 = (gi >> 2) & 31, A2 = gi >> 7;
    const float* srow = sA + (A2 * 32 + B2) * 16;
    const float* g3 = p3 + ((a3 * 2 + b3) * 16) * 16;
    float tmp[16];
#pragma unroll
    for (int r3 = 0; r3 < 16; r3++) {
      float s = 0.f;
#pragma unroll
      for (int r2 = 0; r2 < 16; r2++) s += srow[r2] * g3[r2 * 16 + r3];
      tmp[r3] = s;
    }
#pragma unroll
    for (int ab = 0; ab < 4; ab++) {
      int a4 = ab >> 1, b4 = ab & 1;
      const float* g4 = p4 + (ab * 16) * 16;
      int AL = A2 * 4 + a3 * 2 + a4;
      int BL = B2 * 4 + b3 * 2 + b4;
      float* drow = L4 + (AL * 128 + BL) * 16;
#pragma unroll
      for (int r4 = 0; r4 < 16; r4++) {
        float s = 0.f;
#pragma unroll
        for (int r3 = 0; r3 < 16; r3++) s += tmp[r3] * g4[r3 * 16 + r4];
        drow[r4] = s;
      }
    }
  } else {
    for (int i = tid; i < 64; i += 256) sA[i] = p8[i];
    __syncthreads();
    // k=7 (bond-swapped)
    for (int i = tid; i < 256; i += 256) {
      int rl = i & 15, t = i >> 4;
      int Bt = t & 3, At = t >> 2;
      int a = At >> 1, Ap = At & 1, b = Bt >> 1, Bp = Bt & 1;
      const float* srow = sA + (Ap * 2 + Bp) * 16;
      const float* g = p7 + ((a * 2 + b) * 16) * 16 + rl;
      float s = 0.f;
#pragma unroll
      for (int rk = 0; rk < 16; rk++) s += srow[rk] * g[rk * 16];
      sB[i] = s;
    }
    __syncthreads();
    // k=6
    for (int i = tid; i < 1024; i += 256) {
      int rl = i & 15, t = i >> 4;
      int Bt = t & 7, At = t >> 3;
      int a = At >> 2, Ap = At & 3, b = Bt >> 2, Bp = Bt & 3;
      const float* srow = sB + (Ap * 4 + Bp) * 16;
      const float* g = p6 + (((a * 2 + b) * 16) + rl) * 16;
      float s = 0.f;
#pragma unroll
      for (int rk = 0; rk < 16; rk++) s += srow[rk] * g[rk];
      sA[i] = s;
    }
    __syncthreads();
    // k=5
    for (int i = tid; i < 4096; i += 256) {
      int rl = i & 15, t = i >> 4;
      int Bt = t & 15, At = t >> 4;
      int a = At >> 3, Ap = At & 7, b = Bt >> 3, Bp = Bt & 7;
      const float* srow = sA + (Ap * 8 + Bp) * 16;
      const float* g = p5 + (((a * 2 + b) * 16) + rl) * 16;
      float s = 0.f;
#pragma unroll
      for (int rk = 0; rk < 16; rk++) s += srow[rk] * g[rk];
      R[i] = s;
    }
  }
}

// ---------------------------------------------------------------------------
// prep: fused merge (blocks 0..2047) + cast_x (blocks 2048..10239).
// The two halves are independent (L4,R -> Wt  and  x -> xbf); fusing saves
// one dispatch and overlaps their memory traffic.
// ---------------------------------------------------------------------------
__global__ __launch_bounds__(256) void prep_kernel(const float* __restrict__ L4,
                                                   const float* __restrict__ R,
                                                   u16* __restrict__ Wt,
                                                   const float* __restrict__ x,
                                                   u16* __restrict__ xb) {
  if (blockIdx.x < 2048) {
    // merge: Wt[n][k] = sum_r L4[k>>4][n>>4][r] * R[k&15][n&15][r], bf16.
    int t = blockIdx.x * 256 + threadIdx.x;
    int e = t * 8;
    int Af = e & 2047;                        // k index (8-aligned)
    int Bf = e >> 11;                         // n index
    const float* lrow = L4 + ((Af >> 4) * 128 + (Bf >> 4)) * 16;
    float lv[16];
#pragma unroll
    for (int r = 0; r < 16; r++) lv[r] = lrow[r];
    const float* rbase = R + (Bf & 15) * 16;  // + (Af&15)*256
    u16x8 o;
#pragma unroll
    for (int j = 0; j < 8; j++) {
      const float* rrow = rbase + ((Af + j) & 15) * 256;
      float s = 0.f;
#pragma unroll
      for (int r = 0; r < 16; r++) s += lv[r] * rrow[r];
      o[j] = f2bf(s);
    }
    *(u16x8*)(Wt + (size_t)Bf * 2048 + Af) = o;
  } else {
    // cast_x: fp32 -> bf16, 8 elements per thread.
    size_t i = ((size_t)(blockIdx.x - 2048) * 256 + threadIdx.x) * 8;
    float4 u = *(const float4*)(x + i);
    float4 v = *(const float4*)(x + i + 4);
    u16x8 o;
    o[0] = f2bf(u.x); o[1] = f2bf(u.y); o[2] = f2bf(u.z); o[3] = f2bf(u.w);
    o[4] = f2bf(v.x); o[5] = f2bf(v.y); o[6] = f2bf(v.z); o[7] = f2bf(v.w);
    *(u16x8*)(xb + i) = o;
  }
}

// ---------------------------------------------------------------------------
// gemm: C[8192][2048] = A * Wt^T, bf16 in / fp32 out.
// 256x256 tile, BK=64, 8 waves (512 thr), grid = 256 blocks = 1/CU.
//
// Pipeline (T3+T4): per operand a ring of 4 half-tile slots (128 rows x 64 k,
// 16 KiB each; slot(tile t, half h) = 2*(t&1)+h). Wave wr owns rows wr*64 in
// BOTH halves, wave wc owns cols wc*32 in both halves, so each of the 4
// phases per K-tile (ah,bh) = (0,0),(0,1),(1,1),(1,0) touches exactly one
// A-half + one B-half. Liveness: A-h0 dead after p0, B-h1 after p1 (reused
// from regs at p2), A-h1 after p2, B-h0 after p3. Stage order during tile t:
//   p0: B-h0(t+1)  p1: A-h0(t+2)  p2: B-h1(t+2)  p3: A-h1(t+2)
// -> every staged slot is LDS-dead at issue; one vmcnt(6) per K-tile (at p3)
// guarantees tile t+1 fully resident while 3 half-tiles stay in flight.
//
// Swizzle (T2): 128 B rows would be a 32-way conflict on ds_read_b128; full
// 3-bit XOR: LDS slot (row r, octet p) holds global octet p ^ (r&7).
// global_load_lds dest is linear (lane*16); the swizzle is applied on the
// per-lane GLOBAL address (rule #21): lane l fetches octet (l&7)^(l>>3) of
// row (l>>3). Read side: octet = (ks*2 + hl) ^ (r32&7).
//
// A-frag: lane(r32,hl) holds A[r32][ks*16+hl*8+j]; C/D: col=lane&31,
// row=(reg&3)+8*(reg>>2)+4*hl (m74/m101-verified, carried from prior kernel).
// T1: bijective remap -> XCD x gets the 4(by) x 8(bx) rectangle.
// ---------------------------------------------------------------------------
#define SB0() __builtin_amdgcn_sched_barrier(0)

#define STAGE_OP(g, S, h, dsto, gk)                                            \
  __builtin_amdgcn_global_load_lds(                                            \
      (const __attribute__((address_space(1))) void*)(g[h][0] + (gk)),         \
      (__attribute__((address_space(3))) void*)(S + (dsto) + ldst), 16, 0, 0); \
  __builtin_amdgcn_global_load_lds(                                            \
      (const __attribute__((address_space(1))) void*)(g[h][1] + (gk)),         \
      (__attribute__((address_space(3))) void*)(S + (dsto) + ldst + 4096), 16, 0, 0);

#define STAGE_A(h, dsto, gk) STAGE_OP(gA, As, h, dsto, gk)
#define STAGE_B(h, dsto, gk) STAGE_OP(gB, Bs, h, dsto, gk)

#define LOAD_AF(ah, pa)                                                        \
  _Pragma("unroll") for (int m = 0; m < 2; m++)                                \
      _Pragma("unroll") for (int ks = 0; ks < 4; ks++)                         \
          af[m][ks] = *(const bf16x8*)(As + (pa) + (ah) * 8192 + rbA +         \
                                       m * 2048 + ((((ks * 2) + hl) ^ key) * 8));

#define LOAD_BV(bh, pa)                                                        \
  _Pragma("unroll") for (int ks = 0; ks < 4; ks++)                             \
      bv[ks] = *(const bf16x8*)(Bs + (pa) + (bh) * 8192 + rbB +                \
                                ((((ks * 2) + hl) ^ key) * 8));

#define MFMA8(ah, bh)                                                          \
  _Pragma("unroll") for (int ks = 0; ks < 4; ks++) {                           \
    acc[ah][bh][0] = __builtin_amdgcn_mfma_f32_32x32x16_bf16(                  \
        af[0][ks], bv[ks], acc[ah][bh][0], 0, 0, 0);                           \
    acc[ah][bh][1] = __builtin_amdgcn_mfma_f32_32x32x16_bf16(                  \
        af[1][ks], bv[ks], acc[ah][bh][1], 0, 0, 0);                           \
  }

#define PH_MID()                                                               \
  SB0();                                                                       \
  asm volatile("s_barrier" ::: "memory");                                      \
  asm volatile("s_waitcnt lgkmcnt(0)" ::: "memory");                           \
  SB0();                                                                       \
  __builtin_amdgcn_s_setprio(1);

#define PH_END()                                                               \
  __builtin_amdgcn_s_setprio(0);                                               \
  SB0();                                                                       \
  asm volatile("s_barrier" ::: "memory");                                      \
  SB0();

#define PH_END_VM()                                                            \
  __builtin_amdgcn_s_setprio(0);                                               \
  SB0();                                                                       \
  asm volatile("s_waitcnt vmcnt(6)" ::: "memory");                             \
  asm volatile("s_barrier" ::: "memory");                                      \
  SB0();

__global__ __launch_bounds__(512, 2) void gemm_kernel(const u16* __restrict__ A,
                                                      const u16* __restrict__ B,
                                                      float* __restrict__ C) {
  __shared__ alignas(128) u16 As[4 * 8192];   // 64 KiB: 4 half-tile slots
  __shared__ alignas(128) u16 Bs[4 * 8192];   // 64 KiB
  const int tid = threadIdx.x;
  const int lane = tid & 63;
  const int w = tid >> 6;        // wave 0..7
  const int wr = w >> 2;         // M split (0..1)
  const int wc = w & 3;          // N split (0..3)
  const int r32 = lane & 31;
  const int hl = lane >> 5;

  // T1: XCD x <- flat%8 gets by in [4x,4x+4), all 8 bx (A panels 1x per XCD).
  const int F = blockIdx.x + (blockIdx.y << 3);
  const int li = F >> 3;
  const int m0 = ((F & 7) * 4 + (li >> 3)) << 8;
  const int n0 = (li & 7) << 8;

  // staging: lane l writes LDS linear l*16 (row l>>3, octet l&7); fetches
  // global octet (l&7)^(l>>3) of row l>>3 -> swizzle lands in LDS.
  const int srow = lane >> 3;
  const int soct = (lane & 7) ^ srow;
  const u16* gA[2][2];
  const u16* gB[2][2];
#pragma unroll
  for (int h = 0; h < 2; h++)
#pragma unroll
    for (int q = 0; q < 2; q++) {
      int r = h * 128 + q * 64 + w * 8 + srow;
      gA[h][q] = A + (size_t)(m0 + r) * 2048 + soct * 8;
      gB[h][q] = B + (size_t)(n0 + r) * 2048 + soct * 8;
    }
  const int ldst = w * 512;           // u16: wave's 8 stage rows within slot

  const int key = r32 & 7;            // read-side swizzle key
  const int rbA = (wr * 64 + r32) * 64;
  const int rbB = (wc * 32 + r32) * 64;

  f32x16 acc[2][2][2] = {};
  bf16x8 af[2][4], bv[4];

  // Prologue: issue order = steady-state history (oldest first):
  // Ah0(0),Bh1(0),Ah1(0),Bh0(0),Ah0(1),Bh1(1),Ah1(1) -> vmcnt(6) leaves the
  // newest 3 in flight, guarantees tile 0 (first 4 half-tiles) resident.
  STAGE_A(0, 0, 0);      SB0();
  STAGE_B(1, 8192, 0);   SB0();
  STAGE_A(1, 8192, 0);   SB0();
  STAGE_B(0, 0, 0);      SB0();
  STAGE_A(0, 16384, 64); SB0();
  STAGE_B(1, 24576, 64); SB0();
  STAGE_A(1, 24576, 64); SB0();
  asm volatile("s_waitcnt vmcnt(6)" ::: "memory");
  asm volatile("s_barrier" ::: "memory");
  SB0();

  for (int t = 0; t < 32; t++) {
    const int pa = (t & 1) << 14;     // current-parity slot base (u16)
    const int pan = 16384 - pa;       // next-parity slot base
    const int k1 = (t + 1 < 32 ? t + 1 : 31) * 64;  // clamp: tail re-stages
    const int k2 = (t + 2 < 32 ? t + 2 : 31) * 64;  // valid data to dead slots
    // ---- p0: (ah=0,bh=0); stage B-h0(t+1)
    LOAD_AF(0, pa);
    LOAD_BV(0, pa);
    STAGE_B(0, pan, k1);
    PH_MID();
    MFMA8(0, 0);
    PH_END();
    // ---- p1: (0,1) reuse af; stage A-h0(t+2) over A-h0(t) (dead after p0)
    LOAD_BV(1, pa);
    STAGE_A(0, pa, k2);
    PH_MID();
    MFMA8(0, 1);
    PH_END();
    // ---- p2: (1,1) reuse bv; stage B-h1(t+2) over B-h1(t) (dead after p1)
    LOAD_AF(1, pa);
    STAGE_B(1, pa + 8192, k2);
    PH_MID();
    MFMA8(1, 1);
    PH_END();
    // ---- p3: (1,0); stage A-h1(t+2) over A-h1(t) (dead after p2);
    //      counted vmcnt(6) -> tile t+1 resident, 3 half-tiles stay in flight
    LOAD_BV(0, pa);
    STAGE_A(1, pa + 8192, k2);
    PH_MID();
    MFMA8(1, 0);
    PH_END_VM();
  }

  // drain staging DMA before LDS dealloc at endpgm
  asm volatile("s_waitcnt vmcnt(0)" ::: "memory");

#pragma unroll
  for (int ah = 0; ah < 2; ah++)
#pragma unroll
    for (int bh = 0; bh < 2; bh++)
#pragma unroll
      for (int m = 0; m < 2; m++) {
        size_t cbase = (size_t)(m0 + ah * 128 + wr * 64 + m * 32 + 4 * hl) * 2048 +
                       (n0 + bh * 128 + wc * 32 + r32);
#pragma unroll
        for (int reg = 0; reg < 16; reg++) {
          int row = (reg & 3) + 8 * (reg >> 2);   // +4*hl folded into cbase
          __builtin_nontemporal_store(acc[ah][bh][m][reg], C + cbase + (size_t)row * 2048);
        }
      }
}

extern "C" void kernel_launch(void* const* d_in, const int* in_sizes, int n_in,
                              void* d_out, int out_size, void* d_ws, size_t ws_size,
                              hipStream_t stream) {
  const float* x = (const float*)d_in[0];
  const float* p0 = (const float*)d_in[1];
  const float* p1 = (const float*)d_in[2];
  const float* p2 = (const float*)d_in[3];
  const float* p3 = (const float*)d_in[4];
  const float* p4 = (const float*)d_in[5];
  const float* p5 = (const float*)d_in[6];
  const float* p6 = (const float*)d_in[7];
  const float* p7 = (const float*)d_in[8];
  const float* p8 = (const float*)d_in[9];
  char* ws = (char*)d_ws;
  // ws layout (bytes): xbf 33554432 | Wt 8388608 | L4 1048576 | R 16384
  u16* xbf = (u16*)ws;
  u16* Wt = (u16*)(ws + 33554432);
  float* L4 = (float*)(ws + 41943040);
  float* R = (float*)(ws + 42991616);

  build_lr_kernel<<<17, 256, 0, stream>>>(p0, p1, p2, p3, p4, p5, p6, p7, p8, L4, R);
  prep_kernel<<<10240, 256, 0, stream>>>(L4, R, Wt, x, xbf);
  gemm_kernel<<<dim3(8, 32), 512, 0, stream>>>(xbf, Wt, (float*)d_out);
}

// Round 2
// 270.318 us; speedup vs baseline: 1.0026x; 1.0026x over previous
//
#include <hip/hip_runtime.h>
#include <stdint.h>

typedef unsigned short u16;
typedef __bf16 bf16x8 __attribute__((ext_vector_type(8)));
typedef float f32x16 __attribute__((ext_vector_type(16)));
typedef u16 u16x8 __attribute__((ext_vector_type(8)));

__device__ __forceinline__ u16 f2bf(float f) {
  uint32_t u = __float_as_uint(f);
  u += 0x7fffu + ((u >> 16) & 1u);   // round-to-nearest-even
  return (u16)(u >> 16);
}

// ---------------------------------------------------------------------------
// build_lr: blocks 0..15 build L4[A_L(128)][B_L(128)][r4(16)] (fp32, 1 MiB),
//           block 16 builds R[A_R(16)][B_R(16)][r4(16)] (fp32, 16 KiB).
// Digit order: A = a0 most significant ... a8 least. Core 7 is bond-swapped.
// ---------------------------------------------------------------------------
__global__ __launch_bounds__(256) void build_lr_kernel(
    const float* __restrict__ p0, const float* __restrict__ p1,
    const float* __restrict__ p2, const float* __restrict__ p3,
    const float* __restrict__ p4, const float* __restrict__ p5,
    const float* __restrict__ p6, const float* __restrict__ p7,
    const float* __restrict__ p8, float* __restrict__ L4, float* __restrict__ R) {
  __shared__ float sA[16384];
  __shared__ float sB[4096];
  const int tid = threadIdx.x;
  if (blockIdx.x < 16) {
    for (int i = tid; i < 1024; i += 256) sA[i] = p0[i];
    __syncthreads();
    // step1: sA[8][8][16] x p1 -> sB[16][16][16]
    for (int i = tid; i < 4096; i += 256) {
      int r = i & 15, t = i >> 4;
      int Bb = t & 15, Aa = t >> 4;
      int a = Aa & 1, A = Aa >> 1, b = Bb & 1, B = Bb >> 1;
      const float* srow = sA + (A * 8 + B) * 16;
      const float* g = p1 + ((a * 2 + b) * 16) * 16 + r;
      float s = 0.f;
#pragma unroll
      for (int l = 0; l < 16; l++) s += srow[l] * g[l * 16];
      sB[i] = s;
    }
    __syncthreads();
    // step2: sB[16][16][16] x p2 -> sA[32][32][16]
    for (int i = tid; i < 16384; i += 256) {
      int r = i & 15, t = i >> 4;
      int Bb = t & 31, Aa = t >> 5;
      int a = Aa & 1, A = Aa >> 1, b = Bb & 1, B = Bb >> 1;
      const float* srow = sB + (A * 16 + B) * 16;
      const float* g = p2 + ((a * 2 + b) * 16) * 16 + r;
      float s = 0.f;
#pragma unroll
      for (int l = 0; l < 16; l++) s += srow[l] * g[l * 16];
      sA[i] = s;
    }
    __syncthreads();
    // fused steps 3+4
    int gi = blockIdx.x * 256 + tid;  // 0..4095
    int b3 = gi & 1, a3 = (gi >> 1) & 1;
    int B2 = (gi >> 2) & 31, A2 = gi >> 7;
    const float* srow = sA + (A2 * 32 + B2) * 16;
    const float* g3 = p3 + ((a3 * 2 + b3) * 16) * 16;
    float tmp[16];
#pragma unroll
    for (int r3 = 0; r3 < 16; r3++) {
      float s = 0.f;
#pragma unroll
      for (int r2 = 0; r2 < 16; r2++) s += srow[r2] * g3[r2 * 16 + r3];
      tmp[r3] = s;
    }
#pragma unroll
    for (int ab = 0; ab < 4; ab++) {
      int a4 = ab >> 1, b4 = ab & 1;
      const float* g4 = p4 + (ab * 16) * 16;
      int AL = A2 * 4 + a3 * 2 + a4;
      int BL = B2 * 4 + b3 * 2 + b4;
      float* drow = L4 + (AL * 128 + BL) * 16;
#pragma unroll
      for (int r4 = 0; r4 < 16; r4++) {
        float s = 0.f;
#pragma unroll
        for (int r3 = 0; r3 < 16; r3++) s += tmp[r3] * g4[r3 * 16 + r4];
        drow[r4] = s;
      }
    }
  } else {
    for (int i = tid; i < 64; i += 256) sA[i] = p8[i];
    __syncthreads();
    // k=7 (bond-swapped)
    for (int i = tid; i < 256; i += 256) {
      int rl = i & 15, t = i >> 4;
      int Bt = t & 3, At = t >> 2;
      int a = At >> 1, Ap = At & 1, b = Bt >> 1, Bp = Bt & 1;
      const float* srow = sA + (Ap * 2 + Bp) * 16;
      const float* g = p7 + ((a * 2 + b) * 16) * 16 + rl;
      float s = 0.f;
#pragma unroll
      for (int rk = 0; rk < 16; rk++) s += srow[rk] * g[rk * 16];
      sB[i] = s;
    }
    __syncthreads();
    // k=6
    for (int i = tid; i < 1024; i += 256) {
      int rl = i & 15, t = i >> 4;
      int Bt = t & 7, At = t >> 3;
      int a = At >> 2, Ap = At & 3, b = Bt >> 2, Bp = Bt & 3;
      const float* srow = sB + (Ap * 4 + Bp) * 16;
      const float* g = p6 + (((a * 2 + b) * 16) + rl) * 16;
      float s = 0.f;
#pragma unroll
      for (int rk = 0; rk < 16; rk++) s += srow[rk] * g[rk];
      sA[i] = s;
    }
    __syncthreads();
    // k=5
    for (int i = tid; i < 4096; i += 256) {
      int rl = i & 15, t = i >> 4;
      int Bt = t & 15, At = t >> 4;
      int a = At >> 3, Ap = At & 7, b = Bt >> 3, Bp = Bt & 7;
      const float* srow = sA + (Ap * 8 + Bp) * 16;
      const float* g = p5 + (((a * 2 + b) * 16) + rl) * 16;
      float s = 0.f;
#pragma unroll
      for (int rk = 0; rk < 16; rk++) s += srow[rk] * g[rk];
      R[i] = s;
    }
  }
}

// ---------------------------------------------------------------------------
// prep: fused merge (blocks 0..2047) + cast_x (blocks 2048..10239).
// ---------------------------------------------------------------------------
__global__ __launch_bounds__(256) void prep_kernel(const float* __restrict__ L4,
                                                   const float* __restrict__ R,
                                                   u16* __restrict__ Wt,
                                                   const float* __restrict__ x,
                                                   u16* __restrict__ xb) {
  if (blockIdx.x < 2048) {
    // merge: Wt[n][k] = sum_r L4[k>>4][n>>4][r] * R[k&15][n&15][r], bf16.
    int t = blockIdx.x * 256 + threadIdx.x;
    int e = t * 8;
    int Af = e & 2047;                        // k index (8-aligned)
    int Bf = e >> 11;                         // n index
    const float* lrow = L4 + ((Af >> 4) * 128 + (Bf >> 4)) * 16;
    float lv[16];
#pragma unroll
    for (int r = 0; r < 16; r++) lv[r] = lrow[r];
    const float* rbase = R + (Bf & 15) * 16;  // + (Af&15)*256
    u16x8 o;
#pragma unroll
    for (int j = 0; j < 8; j++) {
      const float* rrow = rbase + ((Af + j) & 15) * 256;
      float s = 0.f;
#pragma unroll
      for (int r = 0; r < 16; r++) s += lv[r] * rrow[r];
      o[j] = f2bf(s);
    }
    *(u16x8*)(Wt + (size_t)Bf * 2048 + Af) = o;
  } else {
    // cast_x: fp32 -> bf16, 8 elements per thread.
    size_t i = ((size_t)(blockIdx.x - 2048) * 256 + threadIdx.x) * 8;
    float4 u = *(const float4*)(x + i);
    float4 v = *(const float4*)(x + i + 4);
    u16x8 o;
    o[0] = f2bf(u.x); o[1] = f2bf(u.y); o[2] = f2bf(u.z); o[3] = f2bf(u.w);
    o[4] = f2bf(v.x); o[5] = f2bf(v.y); o[6] = f2bf(v.z); o[7] = f2bf(v.w);
    *(u16x8*)(xb + i) = o;
  }
}

// ---------------------------------------------------------------------------
// gemm: C[8192][2048] = A * Wt^T, bf16 in / fp32 out.
// 256x256 tile, BK=64, 8 waves, grid = 256 blocks = 1/CU.
//
// R1 post-mortem: phase reads were drained (lgkmcnt(0)) before every MFMA ->
// LDS pipe and matrix pipe strictly alternated (6890 cyc/tile vs 2066 MFMA
// floor). R2 fix: software-pipeline frag reads WITHIN the phase ring using
// counted lgkmcnt so younger reads stay in flight under MFMA:
//   p0: issue af(ah0)x8 + bv1x4; lgkm(8)->{bv0,af[0]} done; MFMA; lgkm(4);
//       MFMA (bv1 still in flight)
//   p1: no reads (bv1 drained under p0's MFMA after lgkm(0)=instant)
//   p2: issue af(ah1)x8; split lgkm(4)/lgkm(0)
//   p3: zero waits; after vmcnt(6)+barrier, prefetch bv0(t+1) (pan slot),
//       drains at p0(t+1)'s lgkm(8).
// bv0 (B-half0) is held in registers across the whole tile (p0+p3 use it) ->
// reads/tile 28->24/wave. Barriers 8->4 per tile.
//
// Stage schedule + vmcnt(6) accounting IDENTICAL to R1 (verified passing):
//   p0: B0(t+1)->pan   p1: A0(t+2)->pa   p2: B1(t+2)->pa   p3: A1(t+2)->pa
// queue at p3: [A0(t+1),B1(t+1),A1(t+1),B0(t+1),A0(t+2),B1(t+2),A1(t+2)]
// vmcnt(6) drains through B0(t+1) -> tile t+1 resident, 3 half-tiles in
// flight. Hazard sweep: every slot overwrite is behind drain+barrier of its
// last reader (A0: p0-lgkm+bar < p1-stage; B1: p1-lgkm+bar < p2-stage;
// A1: p2-lgkm+bar < p3-stage; pan-B0 readers drained at prior p0).
//
// Swizzle unchanged (R1-verified): LDS(row r, oct p) = global(r, p^(r&7));
// staging lane l fetches global octet (l&7)^(l>>3), read octet (2ks+hl)^(r&7).
// C/D: col=lane&31, row=(reg&3)+8*(reg>>2)+4*hl.
// ---------------------------------------------------------------------------
#define SB0() __builtin_amdgcn_sched_barrier(0)
#define LGKM(n) asm volatile("s_waitcnt lgkmcnt(" #n ")" ::: "memory")
#define VMCW(n) asm volatile("s_waitcnt vmcnt(" #n ")" ::: "memory")
#define BAR() asm volatile("s_barrier" ::: "memory")

#define STAGE1(Sbase, dsto, gp, uoff)                                          \
  __builtin_amdgcn_global_load_lds(                                            \
      (const __attribute__((address_space(1))) void*)((gp) + (uoff) + pl),     \
      (__attribute__((address_space(3))) void*)((Sbase) + (dsto) + ldst), 16, 0, 0)

#define STAGE_A(h, dsto, gk)                                                   \
  STAGE1(As, (dsto), A, uA + ((h)*128) * 2048 + (gk));                         \
  STAGE1(As, (dsto) + 4096, A, uA + ((h)*128 + 64) * 2048 + (gk))

#define STAGE_B(h, dsto, gk)                                                   \
  STAGE1(Bs, (dsto), B, uB + ((h)*128) * 2048 + (gk));                         \
  STAGE1(Bs, (dsto) + 4096, B, uB + ((h)*128 + 64) * 2048 + (gk))

#define LOAD_AF_H(dst, ah, m, pav)                                             \
  _Pragma("unroll") for (int ks = 0; ks < 4; ks++)                             \
      dst[ks] = *(const bf16x8*)(As + (pav) + (ah)*8192 + rbA + (m)*2048 +     \
                                 (((ks * 2 + hl) ^ key) * 8))

#define LOAD_BV(dst, bh, pav)                                                  \
  _Pragma("unroll") for (int ks = 0; ks < 4; ks++)                             \
      dst[ks] = *(const bf16x8*)(Bs + (pav) + (bh)*8192 + rbB +                \
                                 (((ks * 2 + hl) ^ key) * 8))

#define MFMA4(afh, bvv, accv)                                                  \
  _Pragma("unroll") for (int ks = 0; ks < 4; ks++)                             \
      accv = __builtin_amdgcn_mfma_f32_32x32x16_bf16(afh[ks], bvv[ks], accv, 0, 0, 0)

#define MFMA8I(afarr, bvv, accp)                                               \
  _Pragma("unroll") for (int ks = 0; ks < 4; ks++) {                           \
    accp[0] = __builtin_amdgcn_mfma_f32_32x32x16_bf16(afarr[0][ks], bvv[ks], accp[0], 0, 0, 0); \
    accp[1] = __builtin_amdgcn_mfma_f32_32x32x16_bf16(afarr[1][ks], bvv[ks], accp[1], 0, 0, 0); \
  }

__global__ __launch_bounds__(512, 2) void gemm_kernel(const u16* __restrict__ A,
                                                      const u16* __restrict__ B,
                                                      float* __restrict__ C) {
  __shared__ alignas(128) u16 As[4 * 8192];   // 64 KiB: 4 half-tile slots
  __shared__ alignas(128) u16 Bs[4 * 8192];   // 64 KiB
  const int tid = threadIdx.x;
  const int lane = tid & 63;
  const int w = tid >> 6;        // wave 0..7
  const int wr = w >> 2;         // M split (0..1)
  const int wc = w & 3;          // N split (0..3)
  const int r32 = lane & 31;
  const int hl = lane >> 5;

  // T1: XCD x <- flat%8 gets by in [4x,4x+4), all 8 bx.
  const int F = blockIdx.x + (blockIdx.y << 3);
  const int li = F >> 3;
  const int m0 = ((F & 7) * 4 + (li >> 3)) << 8;
  const int n0 = (li & 7) << 8;

  // staging: lane l -> LDS linear l*16B (row l>>3, oct l&7); global octet
  // soct = (l&7)^(l>>3). Uniform base part in SGPR (uA/uB), per-lane in pl.
  const int srow = lane >> 3;
  const int soct = (lane & 7) ^ srow;
  const int uA = m0 * 2048;
  const int uB = n0 * 2048;
  const int pl = (w * 8 + srow) * 2048 + soct * 8;
  const int ldst = w * 512;           // u16: wave's 8 stage rows within slot

  const int key = r32 & 7;            // read-side swizzle key
  const int rbA = (wr * 64 + r32) * 64;
  const int rbB = (wc * 32 + r32) * 64;

  f32x16 acc[2][2][2] = {};
  bf16x8 af[2][4], bv0[4], bv1[4];

  // Prologue: queue (oldest first) A0(0),B1(0),A1(0),B0(0),A0(1),B1(1),A1(1);
  // vmcnt(6) drains first 8 = tile 0 resident.
  STAGE_A(0, 0, 0);      SB0();
  STAGE_B(1, 8192, 0);   SB0();
  STAGE_A(1, 8192, 0);   SB0();
  STAGE_B(0, 0, 0);      SB0();
  STAGE_A(0, 16384, 64); SB0();
  STAGE_B(1, 24576, 64); SB0();
  STAGE_A(1, 24576, 64); SB0();
  VMCW(6);
  BAR();
  LOAD_BV(bv0, 0, 0);    // bv0(0) in flight into p0's lgkm(8)
  SB0();

#pragma unroll 1
  for (int t = 0; t < 32; t++) {
    const int pav = (t & 1) << 14;    // current-parity slot base (u16)
    const int pnv = 16384 - pav;      // next-parity slot base
    const int k1 = (t < 31 ? t + 1 : 31) * 64;
    const int k2 = (t < 30 ? t + 2 : 31) * 64;
    // ---- p0: C00 = af(ah0)·bv0; stage B0(t+1)->pan
    STAGE_B(0, pnv, k1);
    SB0();
    LOAD_AF_H(af[0], 0, 0, pav); SB0();
    LOAD_AF_H(af[1], 0, 1, pav); SB0();
    LOAD_BV(bv1, 1, pav);
    LGKM(8); SB0();                   // bv0 + af[0] done; af[1],bv1 in flight
    __builtin_amdgcn_s_setprio(1);
    MFMA4(af[0], bv0, acc[0][0][0]);
    LGKM(4); SB0();                   // af[1] done; bv1 in flight
    MFMA4(af[1], bv0, acc[0][0][1]);
    __builtin_amdgcn_s_setprio(0);
    BAR();
    // ---- p1: C01 = af·bv1; stage A0(t+2)->pa (af reads drained at p0)
    STAGE_A(0, pav, k2);
    LGKM(0); SB0();                   // bv1 (drained under p0's MFMA)
    __builtin_amdgcn_s_setprio(1);
    MFMA8I(af, bv1, acc[0][1]);
    __builtin_amdgcn_s_setprio(0);
    BAR();
    // ---- p2: C11 = af(ah1)·bv1; stage B1(t+2)->pa (bv1 drained at p1)
    STAGE_B(1, pav + 8192, k2);
    SB0();
    LOAD_AF_H(af[0], 1, 0, pav); SB0();
    LOAD_AF_H(af[1], 1, 1, pav);
    LGKM(4); SB0();                   // af[0] done; af[1] in flight
    __builtin_amdgcn_s_setprio(1);
    MFMA4(af[0], bv1, acc[1][1][0]);
    LGKM(0); SB0();
    MFMA4(af[1], bv1, acc[1][1][1]);
    __builtin_amdgcn_s_setprio(0);
    BAR();
    // ---- p3: C10 = af·bv0 (all frags resident, zero waits);
    //      stage A1(t+2)->pa; vmcnt(6)-gate; prefetch bv0(t+1) from pan
    STAGE_A(1, pav + 8192, k2);
    SB0();
    __builtin_amdgcn_s_setprio(1);
    MFMA8I(af, bv0, acc[1][0]);
    __builtin_amdgcn_s_setprio(0);
    VMCW(6);                          // tile t+1 fully landed (thru B0(t+1))
    BAR();                            // all waves' t+1 stages visible
    LOAD_BV(bv0, 0, pnv);             // bv0(t+1); drains at p0's lgkm(8)
    SB0();
  }

  // drain staging DMA before LDS dealloc at endpgm
  VMCW(0);

#pragma unroll
  for (int ah = 0; ah < 2; ah++)
#pragma unroll
    for (int bh = 0; bh < 2; bh++)
#pragma unroll
      for (int m = 0; m < 2; m++) {
        size_t cbase = (size_t)(m0 + ah * 128 + wr * 64 + m * 32 + 4 * hl) * 2048 +
                       (n0 + bh * 128 + wc * 32 + r32);
#pragma unroll
        for (int reg = 0; reg < 16; reg++) {
          int row = (reg & 3) + 8 * (reg >> 2);   // +4*hl folded into cbase
          __builtin_nontemporal_store(acc[ah][bh][m][reg], C + cbase + (size_t)row * 2048);
        }
      }
}

extern "C" void kernel_launch(void* const* d_in, const int* in_sizes, int n_in,
                              void* d_out, int out_size, void* d_ws, size_t ws_size,
                              hipStream_t stream) {
  const float* x = (const float*)d_in[0];
  const float* p0 = (const float*)d_in[1];
  const float* p1 = (const float*)d_in[2];
  const float* p2 = (const float*)d_in[3];
  const float* p3 = (const float*)d_in[4];
  const float* p4 = (const float*)d_in[5];
  const float* p5 = (const float*)d_in[6];
  const float* p6 = (const float*)d_in[7];
  const float* p7 = (const float*)d_in[8];
  const float* p8 = (const float*)d_in[9];
  char* ws = (char*)d_ws;
  // ws layout (bytes): xbf 33554432 | Wt 8388608 | L4 1048576 | R 16384
  u16* xbf = (u16*)ws;
  u16* Wt = (u16*)(ws + 33554432);
  float* L4 = (float*)(ws + 41943040);
  float* R = (float*)(ws + 42991616);

  build_lr_kernel<<<17, 256, 0, stream>>>(p0, p1, p2, p3, p4, p5, p6, p7, p8, L4, R);
  prep_kernel<<<10240, 256, 0, stream>>>(L4, R, Wt, x, xbf);
  gemm_kernel<<<dim3(8, 32), 512, 0, stream>>>(xbf, Wt, (float*)d_out);
}

// Round 3
// 224.672 us; speedup vs baseline: 1.2063x; 1.2032x over previous
//
#include <hip/hip_runtime.h>
#include <stdint.h>

typedef unsigned short u16;
typedef __bf16 bf16x8 __attribute__((ext_vector_type(8)));
typedef float f32x16 __attribute__((ext_vector_type(16)));
typedef u16 u16x8 __attribute__((ext_vector_type(8)));

__device__ __forceinline__ u16 f2bf(float f) {
  uint32_t u = __float_as_uint(f);
  u += 0x7fffu + ((u >> 16) & 1u);   // round-to-nearest-even
  return (u16)(u >> 16);
}

// ---------------------------------------------------------------------------
// build_lr (R3 rewrite): was 148 us at 0.6% VALUBusy / 0.7% occupancy --
// 17 blocks serially recomputing dependent stages. Now one thread per output
// pair; the whole 4-stage chain is thread-local in registers, cores staged
// once into LDS. Summation order per stage unchanged (ascending l) ->
// bit-identical f32 results.
//   blocks 0..63 : L4[AL(128)][BL(128)][r4(16)], thread = (AL,BL),
//                  t_k[r] = sum_l t_{k-1}[l] * pk[(ak*2+bk)][l][r]
//                  AL bits: a0(3)|a1|a2|a3|a4 ; BL likewise.
//   block 64     : R[AR(16)][BR(16)][r(16)], thread = (AR,BR); p7 is
//                  bond-swapped (contract 3rd dim, emit 4th), p6/p5 contract
//                  their 4th dim (fast) emitting 3rd.
// ---------------------------------------------------------------------------
__global__ __launch_bounds__(256) void build_lr_kernel(
    const float* __restrict__ p0, const float* __restrict__ p1,
    const float* __restrict__ p2, const float* __restrict__ p3,
    const float* __restrict__ p4, const float* __restrict__ p5,
    const float* __restrict__ p6, const float* __restrict__ p7,
    const float* __restrict__ p8, float* __restrict__ L4, float* __restrict__ R) {
  __shared__ float sC[5 * 1024];   // L4 path: p0..p4 | R path: p5,p6,p7,p8
  const int tid = threadIdx.x;
  if (blockIdx.x < 64) {
    for (int i = tid; i < 1024; i += 256) {
      sC[i]        = p0[i];
      sC[1024 + i] = p1[i];
      sC[2048 + i] = p2[i];
      sC[3072 + i] = p3[i];
      sC[4096 + i] = p4[i];
    }
    __syncthreads();
    const int idx = blockIdx.x * 256 + tid;   // AL*128 + BL
    const int AL = idx >> 7, BL = idx & 127;
    float t[16], u[16];
    const float* c0 = sC + ((AL >> 4) * 8 + (BL >> 4)) * 16;
#pragma unroll
    for (int l = 0; l < 16; l++) t[l] = c0[l];
#pragma unroll
    for (int k = 0; k < 4; k++) {
      const int ak = (AL >> (3 - k)) & 1;
      const int bk = (BL >> (3 - k)) & 1;
      const float* ck = sC + (k + 1) * 1024 + ((ak * 2 + bk) << 8);
#pragma unroll
      for (int r = 0; r < 16; r++) u[r] = 0.f;
#pragma unroll
      for (int l = 0; l < 16; l++) {
        const float tv = t[l];
#pragma unroll
        for (int r = 0; r < 16; r++) u[r] += tv * ck[l * 16 + r];
      }
#pragma unroll
      for (int r = 0; r < 16; r++) t[r] = u[r];
    }
    float4* dst = (float4*)(L4 + (size_t)idx * 16);
#pragma unroll
    for (int j = 0; j < 4; j++)
      dst[j] = make_float4(t[4 * j], t[4 * j + 1], t[4 * j + 2], t[4 * j + 3]);
  } else {
    for (int i = tid; i < 1024; i += 256) {
      sC[i]        = p5[i];
      sC[1024 + i] = p6[i];
      sC[2048 + i] = p7[i];
    }
    for (int i = tid; i < 64; i += 256) sC[3072 + i] = p8[i];
    __syncthreads();
    const int AR = tid >> 4, BR = tid & 15;
    const int a5 = AR >> 3, a6 = (AR >> 2) & 1, a7 = (AR >> 1) & 1, a8 = AR & 1;
    const int b5 = BR >> 3, b6 = (BR >> 2) & 1, b7 = (BR >> 1) & 1, b8 = BR & 1;
    float t[16], u[16];
    const float* c8 = sC + 3072 + (a8 * 2 + b8) * 16;
#pragma unroll
    for (int l = 0; l < 16; l++) t[l] = c8[l];
    // stage 7 (bond-swapped): u[y] = sum_z t[z] * p7[(a7,b7)][z][y]
    const float* c7 = sC + 2048 + ((a7 * 2 + b7) << 8);
#pragma unroll
    for (int r = 0; r < 16; r++) u[r] = 0.f;
#pragma unroll
    for (int z = 0; z < 16; z++) {
      const float tv = t[z];
#pragma unroll
      for (int y = 0; y < 16; y++) u[y] += tv * c7[z * 16 + y];
    }
#pragma unroll
    for (int r = 0; r < 16; r++) t[r] = u[r];
    // stage 6: u[rl] = sum_rk t[rk] * p6[(a6,b6)][rl][rk]
    const float* c6 = sC + 1024 + ((a6 * 2 + b6) << 8);
#pragma unroll
    for (int rl = 0; rl < 16; rl++) {
      float s = 0.f;
#pragma unroll
      for (int rk = 0; rk < 16; rk++) s += t[rk] * c6[rl * 16 + rk];
      u[rl] = s;
    }
#pragma unroll
    for (int r = 0; r < 16; r++) t[r] = u[r];
    // stage 5: R[(AR*16+BR)*16+rl] = sum_rk t[rk] * p5[(a5,b5)][rl][rk]
    const float* c5 = sC + ((a5 * 2 + b5) << 8);
#pragma unroll
    for (int rl = 0; rl < 16; rl++) {
      float s = 0.f;
#pragma unroll
      for (int rk = 0; rk < 16; rk++) s += t[rk] * c5[rl * 16 + rk];
      R[tid * 16 + rl] = s;
    }
  }
}

// ---------------------------------------------------------------------------
// prep: fused merge (blocks 0..2047) + cast_x (blocks 2048..10239).
// ---------------------------------------------------------------------------
__global__ __launch_bounds__(256) void prep_kernel(const float* __restrict__ L4,
                                                   const float* __restrict__ R,
                                                   u16* __restrict__ Wt,
                                                   const float* __restrict__ x,
                                                   u16* __restrict__ xb) {
  if (blockIdx.x < 2048) {
    // merge: Wt[n][k] = sum_r L4[k>>4][n>>4][r] * R[k&15][n&15][r], bf16.
    int t = blockIdx.x * 256 + threadIdx.x;
    int e = t * 8;
    int Af = e & 2047;                        // k index (8-aligned)
    int Bf = e >> 11;                         // n index
    const float* lrow = L4 + ((Af >> 4) * 128 + (Bf >> 4)) * 16;
    float lv[16];
#pragma unroll
    for (int r = 0; r < 16; r++) lv[r] = lrow[r];
    const float* rbase = R + (Bf & 15) * 16;  // + (Af&15)*256
    u16x8 o;
#pragma unroll
    for (int j = 0; j < 8; j++) {
      const float* rrow = rbase + ((Af + j) & 15) * 256;
      float s = 0.f;
#pragma unroll
      for (int r = 0; r < 16; r++) s += lv[r] * rrow[r];
      o[j] = f2bf(s);
    }
    *(u16x8*)(Wt + (size_t)Bf * 2048 + Af) = o;
  } else {
    // cast_x: fp32 -> bf16, 8 elements per thread.
    size_t i = ((size_t)(blockIdx.x - 2048) * 256 + threadIdx.x) * 8;
    float4 u = *(const float4*)(x + i);
    float4 v = *(const float4*)(x + i + 4);
    u16x8 o;
    o[0] = f2bf(u.x); o[1] = f2bf(u.y); o[2] = f2bf(u.z); o[3] = f2bf(u.w);
    o[4] = f2bf(v.x); o[5] = f2bf(v.y); o[6] = f2bf(v.z); o[7] = f2bf(v.w);
    *(u16x8*)(xb + i) = o;
  }
}

// ---------------------------------------------------------------------------
// gemm: C[8192][2048] = A * Wt^T, bf16 in / fp32 out.  (unchanged from R2)
// 256x256 tile, BK=64, 8 waves, grid = 256 blocks = 1/CU.
// In-phase software pipeline with counted lgkmcnt; bv0 held in registers
// across the tile; stage schedule + vmcnt(6) accounting as R1 (verified).
// Swizzle: LDS(row r, oct p) = global(r, p^(r&7)); staging lane l fetches
// global octet (l&7)^(l>>3); read octet (2ks+hl)^(r&7).
// C/D: col=lane&31, row=(reg&3)+8*(reg>>2)+4*hl.
// ---------------------------------------------------------------------------
#define SB0() __builtin_amdgcn_sched_barrier(0)
#define LGKM(n) asm volatile("s_waitcnt lgkmcnt(" #n ")" ::: "memory")
#define VMCW(n) asm volatile("s_waitcnt vmcnt(" #n ")" ::: "memory")
#define BAR() asm volatile("s_barrier" ::: "memory")

#define STAGE1(Sbase, dsto, gp, uoff)                                          \
  __builtin_amdgcn_global_load_lds(                                            \
      (const __attribute__((address_space(1))) void*)((gp) + (uoff) + pl),     \
      (__attribute__((address_space(3))) void*)((Sbase) + (dsto) + ldst), 16, 0, 0)

#define STAGE_A(h, dsto, gk)                                                   \
  STAGE1(As, (dsto), A, uA + ((h)*128) * 2048 + (gk));                         \
  STAGE1(As, (dsto) + 4096, A, uA + ((h)*128 + 64) * 2048 + (gk))

#define STAGE_B(h, dsto, gk)                                                   \
  STAGE1(Bs, (dsto), B, uB + ((h)*128) * 2048 + (gk));                         \
  STAGE1(Bs, (dsto) + 4096, B, uB + ((h)*128 + 64) * 2048 + (gk))

#define LOAD_AF_H(dst, ah, m, pav)                                             \
  _Pragma("unroll") for (int ks = 0; ks < 4; ks++)                             \
      dst[ks] = *(const bf16x8*)(As + (pav) + (ah)*8192 + rbA + (m)*2048 +     \
                                 (((ks * 2 + hl) ^ key) * 8))

#define LOAD_BV(dst, bh, pav)                                                  \
  _Pragma("unroll") for (int ks = 0; ks < 4; ks++)                             \
      dst[ks] = *(const bf16x8*)(Bs + (pav) + (bh)*8192 + rbB +                \
                                 (((ks * 2 + hl) ^ key) * 8))

#define MFMA4(afh, bvv, accv)                                                  \
  _Pragma("unroll") for (int ks = 0; ks < 4; ks++)                             \
      accv = __builtin_amdgcn_mfma_f32_32x32x16_bf16(afh[ks], bvv[ks], accv, 0, 0, 0)

#define MFMA8I(afarr, bvv, accp)                                               \
  _Pragma("unroll") for (int ks = 0; ks < 4; ks++) {                           \
    accp[0] = __builtin_amdgcn_mfma_f32_32x32x16_bf16(afarr[0][ks], bvv[ks], accp[0], 0, 0, 0); \
    accp[1] = __builtin_amdgcn_mfma_f32_32x32x16_bf16(afarr[1][ks], bvv[ks], accp[1], 0, 0, 0); \
  }

__global__ __launch_bounds__(512, 2) void gemm_kernel(const u16* __restrict__ A,
                                                      const u16* __restrict__ B,
                                                      float* __restrict__ C) {
  __shared__ alignas(128) u16 As[4 * 8192];   // 64 KiB: 4 half-tile slots
  __shared__ alignas(128) u16 Bs[4 * 8192];   // 64 KiB
  const int tid = threadIdx.x;
  const int lane = tid & 63;
  const int w = tid >> 6;        // wave 0..7
  const int wr = w >> 2;         // M split (0..1)
  const int wc = w & 3;          // N split (0..3)
  const int r32 = lane & 31;
  const int hl = lane >> 5;

  // T1: XCD x <- flat%8 gets by in [4x,4x+4), all 8 bx.
  const int F = blockIdx.x + (blockIdx.y << 3);
  const int li = F >> 3;
  const int m0 = ((F & 7) * 4 + (li >> 3)) << 8;
  const int n0 = (li & 7) << 8;

  // staging: lane l -> LDS linear l*16B (row l>>3, oct l&7); global octet
  // soct = (l&7)^(l>>3). Uniform base part in SGPR (uA/uB), per-lane in pl.
  const int srow = lane >> 3;
  const int soct = (lane & 7) ^ srow;
  const int uA = m0 * 2048;
  const int uB = n0 * 2048;
  const int pl = (w * 8 + srow) * 2048 + soct * 8;
  const int ldst = w * 512;           // u16: wave's 8 stage rows within slot

  const int key = r32 & 7;            // read-side swizzle key
  const int rbA = (wr * 64 + r32) * 64;
  const int rbB = (wc * 32 + r32) * 64;

  f32x16 acc[2][2][2] = {};
  bf16x8 af[2][4], bv0[4], bv1[4];

  // Prologue: queue (oldest first) A0(0),B1(0),A1(0),B0(0),A0(1),B1(1),A1(1);
  // vmcnt(6) drains first 8 = tile 0 resident.
  STAGE_A(0, 0, 0);      SB0();
  STAGE_B(1, 8192, 0);   SB0();
  STAGE_A(1, 8192, 0);   SB0();
  STAGE_B(0, 0, 0);      SB0();
  STAGE_A(0, 16384, 64); SB0();
  STAGE_B(1, 24576, 64); SB0();
  STAGE_A(1, 24576, 64); SB0();
  VMCW(6);
  BAR();
  LOAD_BV(bv0, 0, 0);    // bv0(0) in flight into p0's lgkm(8)
  SB0();

#pragma unroll 1
  for (int t = 0; t < 32; t++) {
    const int pav = (t & 1) << 14;    // current-parity slot base (u16)
    const int pnv = 16384 - pav;      // next-parity slot base
    const int k1 = (t < 31 ? t + 1 : 31) * 64;
    const int k2 = (t < 30 ? t + 2 : 31) * 64;
    // ---- p0: C00 = af(ah0)·bv0; stage B0(t+1)->pan
    STAGE_B(0, pnv, k1);
    SB0();
    LOAD_AF_H(af[0], 0, 0, pav); SB0();
    LOAD_AF_H(af[1], 0, 1, pav); SB0();
    LOAD_BV(bv1, 1, pav);
    LGKM(8); SB0();                   // bv0 + af[0] done; af[1],bv1 in flight
    __builtin_amdgcn_s_setprio(1);
    MFMA4(af[0], bv0, acc[0][0][0]);
    LGKM(4); SB0();                   // af[1] done; bv1 in flight
    MFMA4(af[1], bv0, acc[0][0][1]);
    __builtin_amdgcn_s_setprio(0);
    BAR();
    // ---- p1: C01 = af·bv1; stage A0(t+2)->pa (af reads drained at p0)
    STAGE_A(0, pav, k2);
    LGKM(0); SB0();                   // bv1 (drained under p0's MFMA)
    __builtin_amdgcn_s_setprio(1);
    MFMA8I(af, bv1, acc[0][1]);
    __builtin_amdgcn_s_setprio(0);
    BAR();
    // ---- p2: C11 = af(ah1)·bv1; stage B1(t+2)->pa (bv1 drained at p1)
    STAGE_B(1, pav + 8192, k2);
    SB0();
    LOAD_AF_H(af[0], 1, 0, pav); SB0();
    LOAD_AF_H(af[1], 1, 1, pav);
    LGKM(4); SB0();                   // af[0] done; af[1] in flight
    __builtin_amdgcn_s_setprio(1);
    MFMA4(af[0], bv1, acc[1][1][0]);
    LGKM(0); SB0();
    MFMA4(af[1], bv1, acc[1][1][1]);
    __builtin_amdgcn_s_setprio(0);
    BAR();
    // ---- p3: C10 = af·bv0 (all frags resident, zero waits);
    //      stage A1(t+2)->pa; vmcnt(6)-gate; prefetch bv0(t+1) from pan
    STAGE_A(1, pav + 8192, k2);
    SB0();
    __builtin_amdgcn_s_setprio(1);
    MFMA8I(af, bv0, acc[1][0]);
    __builtin_amdgcn_s_setprio(0);
    VMCW(6);                          // tile t+1 fully landed (thru B0(t+1))
    BAR();                            // all waves' t+1 stages visible
    LOAD_BV(bv0, 0, pnv);             // bv0(t+1); drains at p0's lgkm(8)
    SB0();
  }

  // drain staging DMA before LDS dealloc at endpgm
  VMCW(0);

#pragma unroll
  for (int ah = 0; ah < 2; ah++)
#pragma unroll
    for (int bh = 0; bh < 2; bh++)
#pragma unroll
      for (int m = 0; m < 2; m++) {
        size_t cbase = (size_t)(m0 + ah * 128 + wr * 64 + m * 32 + 4 * hl) * 2048 +
                       (n0 + bh * 128 + wc * 32 + r32);
#pragma unroll
        for (int reg = 0; reg < 16; reg++) {
          int row = (reg & 3) + 8 * (reg >> 2);   // +4*hl folded into cbase
          __builtin_nontemporal_store(acc[ah][bh][m][reg], C + cbase + (size_t)row * 2048);
        }
      }
}

extern "C" void kernel_launch(void* const* d_in, const int* in_sizes, int n_in,
                              void* d_out, int out_size, void* d_ws, size_t ws_size,
                              hipStream_t stream) {
  const float* x = (const float*)d_in[0];
  const float* p0 = (const float*)d_in[1];
  const float* p1 = (const float*)d_in[2];
  const float* p2 = (const float*)d_in[3];
  const float* p3 = (const float*)d_in[4];
  const float* p4 = (const float*)d_in[5];
  const float* p5 = (const float*)d_in[6];
  const float* p6 = (const float*)d_in[7];
  const float* p7 = (const float*)d_in[8];
  const float* p8 = (const float*)d_in[9];
  char* ws = (char*)d_ws;
  // ws layout (bytes): xbf 33554432 | Wt 8388608 | L4 1048576 | R 16384
  u16* xbf = (u16*)ws;
  u16* Wt = (u16*)(ws + 33554432);
  float* L4 = (float*)(ws + 41943040);
  float* R = (float*)(ws + 42991616);

  build_lr_kernel<<<65, 256, 0, stream>>>(p0, p1, p2, p3, p4, p5, p6, p7, p8, L4, R);
  prep_kernel<<<10240, 256, 0, stream>>>(L4, R, Wt, x, xbf);
  gemm_kernel<<<dim3(8, 32), 512, 0, stream>>>(xbf, Wt, (float*)d_out);
}

// Round 4
// 220.210 us; speedup vs baseline: 1.2308x; 1.0203x over previous
//
#include <hip/hip_runtime.h>
#include <stdint.h>

typedef unsigned short u16;
typedef __bf16 bf16x8 __attribute__((ext_vector_type(8)));
typedef float f32x16 __attribute__((ext_vector_type(16)));
typedef u16 u16x8 __attribute__((ext_vector_type(8)));

__device__ __forceinline__ u16 f2bf(float f) {
  uint32_t u = __float_as_uint(f);
  u += 0x7fffu + ((u >> 16) & 1u);   // round-to-nearest-even
  return (u16)(u >> 16);
}

// ---------------------------------------------------------------------------
// build_lr (R3-verified): one thread per output pair, 4-stage chain in
// registers, cores staged once into LDS. Ascending-l summation -> bit-
// identical f32 vs original.
// ---------------------------------------------------------------------------
__global__ __launch_bounds__(256) void build_lr_kernel(
    const float* __restrict__ p0, const float* __restrict__ p1,
    const float* __restrict__ p2, const float* __restrict__ p3,
    const float* __restrict__ p4, const float* __restrict__ p5,
    const float* __restrict__ p6, const float* __restrict__ p7,
    const float* __restrict__ p8, float* __restrict__ L4, float* __restrict__ R) {
  __shared__ float sC[5 * 1024];   // L4 path: p0..p4 | R path: p5,p6,p7,p8
  const int tid = threadIdx.x;
  if (blockIdx.x < 64) {
    for (int i = tid; i < 1024; i += 256) {
      sC[i]        = p0[i];
      sC[1024 + i] = p1[i];
      sC[2048 + i] = p2[i];
      sC[3072 + i] = p3[i];
      sC[4096 + i] = p4[i];
    }
    __syncthreads();
    const int idx = blockIdx.x * 256 + tid;   // AL*128 + BL
    const int AL = idx >> 7, BL = idx & 127;
    float t[16], u[16];
    const float* c0 = sC + ((AL >> 4) * 8 + (BL >> 4)) * 16;
#pragma unroll
    for (int l = 0; l < 16; l++) t[l] = c0[l];
#pragma unroll
    for (int k = 0; k < 4; k++) {
      const int ak = (AL >> (3 - k)) & 1;
      const int bk = (BL >> (3 - k)) & 1;
      const float* ck = sC + (k + 1) * 1024 + ((ak * 2 + bk) << 8);
#pragma unroll
      for (int r = 0; r < 16; r++) u[r] = 0.f;
#pragma unroll
      for (int l = 0; l < 16; l++) {
        const float tv = t[l];
#pragma unroll
        for (int r = 0; r < 16; r++) u[r] += tv * ck[l * 16 + r];
      }
#pragma unroll
      for (int r = 0; r < 16; r++) t[r] = u[r];
    }
    float4* dst = (float4*)(L4 + (size_t)idx * 16);
#pragma unroll
    for (int j = 0; j < 4; j++)
      dst[j] = make_float4(t[4 * j], t[4 * j + 1], t[4 * j + 2], t[4 * j + 3]);
  } else {
    for (int i = tid; i < 1024; i += 256) {
      sC[i]        = p5[i];
      sC[1024 + i] = p6[i];
      sC[2048 + i] = p7[i];
    }
    for (int i = tid; i < 64; i += 256) sC[3072 + i] = p8[i];
    __syncthreads();
    const int AR = tid >> 4, BR = tid & 15;
    const int a5 = AR >> 3, a6 = (AR >> 2) & 1, a7 = (AR >> 1) & 1, a8 = AR & 1;
    const int b5 = BR >> 3, b6 = (BR >> 2) & 1, b7 = (BR >> 1) & 1, b8 = BR & 1;
    float t[16], u[16];
    const float* c8 = sC + 3072 + (a8 * 2 + b8) * 16;
#pragma unroll
    for (int l = 0; l < 16; l++) t[l] = c8[l];
    // stage 7 (bond-swapped): u[y] = sum_z t[z] * p7[(a7,b7)][z][y]
    const float* c7 = sC + 2048 + ((a7 * 2 + b7) << 8);
#pragma unroll
    for (int r = 0; r < 16; r++) u[r] = 0.f;
#pragma unroll
    for (int z = 0; z < 16; z++) {
      const float tv = t[z];
#pragma unroll
      for (int y = 0; y < 16; y++) u[y] += tv * c7[z * 16 + y];
    }
#pragma unroll
    for (int r = 0; r < 16; r++) t[r] = u[r];
    // stage 6: u[rl] = sum_rk t[rk] * p6[(a6,b6)][rl][rk]
    const float* c6 = sC + 1024 + ((a6 * 2 + b6) << 8);
#pragma unroll
    for (int rl = 0; rl < 16; rl++) {
      float s = 0.f;
#pragma unroll
      for (int rk = 0; rk < 16; rk++) s += t[rk] * c6[rl * 16 + rk];
      u[rl] = s;
    }
#pragma unroll
    for (int r = 0; r < 16; r++) t[r] = u[r];
    // stage 5: R[(AR*16+BR)*16+rl] = sum_rk t[rk] * p5[(a5,b5)][rl][rk]
    const float* c5 = sC + ((a5 * 2 + b5) << 8);
#pragma unroll
    for (int rl = 0; rl < 16; rl++) {
      float s = 0.f;
#pragma unroll
      for (int rk = 0; rk < 16; rk++) s += t[rk] * c5[rl * 16 + rk];
      R[tid * 16 + rl] = s;
    }
  }
}

// ---------------------------------------------------------------------------
// prep: fused merge (blocks 0..2047) + cast_x (blocks 2048..10239).
// ---------------------------------------------------------------------------
__global__ __launch_bounds__(256) void prep_kernel(const float* __restrict__ L4,
                                                   const float* __restrict__ R,
                                                   u16* __restrict__ Wt,
                                                   const float* __restrict__ x,
                                                   u16* __restrict__ xb) {
  if (blockIdx.x < 2048) {
    // merge: Wt[n][k] = sum_r L4[k>>4][n>>4][r] * R[k&15][n&15][r], bf16.
    int t = blockIdx.x * 256 + threadIdx.x;
    int e = t * 8;
    int Af = e & 2047;                        // k index (8-aligned)
    int Bf = e >> 11;                         // n index
    const float* lrow = L4 + ((Af >> 4) * 128 + (Bf >> 4)) * 16;
    float lv[16];
#pragma unroll
    for (int r = 0; r < 16; r++) lv[r] = lrow[r];
    const float* rbase = R + (Bf & 15) * 16;  // + (Af&15)*256
    u16x8 o;
#pragma unroll
    for (int j = 0; j < 8; j++) {
      const float* rrow = rbase + ((Af + j) & 15) * 256;
      float s = 0.f;
#pragma unroll
      for (int r = 0; r < 16; r++) s += lv[r] * rrow[r];
      o[j] = f2bf(s);
    }
    *(u16x8*)(Wt + (size_t)Bf * 2048 + Af) = o;
  } else {
    // cast_x: fp32 -> bf16, 8 elements per thread.
    size_t i = ((size_t)(blockIdx.x - 2048) * 256 + threadIdx.x) * 8;
    float4 u = *(const float4*)(x + i);
    float4 v = *(const float4*)(x + i + 4);
    u16x8 o;
    o[0] = f2bf(u.x); o[1] = f2bf(u.y); o[2] = f2bf(u.z); o[3] = f2bf(u.w);
    o[4] = f2bf(v.x); o[5] = f2bf(v.y); o[6] = f2bf(v.z); o[7] = f2bf(v.w);
    *(u16x8*)(xb + i) = o;
  }
}

// ---------------------------------------------------------------------------
// gemm: C[8192][2048] = A * Wt^T, bf16 in / fp32 out.
// 256x256 tile, BK=64, 8 waves, 1 block/CU, grid = 256 blocks.
//
// R3 post-mortem: R1 (drain) and R2 (counted-lgkm) both ~31% MfmaUtil --
// frag reads were issued in the SAME phase that consumed them, so the 8-wave
// read burst (~1150 cyc LDS-port time) strictly alternated with the MFMA
// burst. R4: k-slice phases with reads ONE PHASE AHEAD:
//   phase p: [reads for ks=p+1] -> LGKM(6) (drains ks=p reads, issued a full
//   phase ago = free; the 6 new reads stay in flight UNDER the MFMAs)
//   -> 8 MFMAs at ks=p (all 8 acc frags = 8 independent depth-1 chains).
// Staging: all phases read all 4 slots, so slots die only at p3's lgkm ->
// single stage burst: p0 stages tile t+1's 4 half-tiles into the other
// parity; p3 gates with vmcnt(0)+barrier (exact: nothing newer in flight;
// issued 3 phases ~1950 cyc earlier) then reads ks0(t+1) from the new slots.
// Barriers: 2 per K-tile (both in p3). Hazards: tile-t slots last read at
// p2 (ks3), drained at every wave's p3-LGKM(6) before p3's closing barrier;
// t+2 staging (p0 of t+1) starts only after that barrier. Register sets
// S0/S1 alternate per phase (static names, rule #20).
//
// Swizzle (R1/R2-verified): LDS(row r, oct p) = global(r, p^(r&7)); staging
// lane l fetches global octet (l&7)^(l>>3); read octet (2ks+hl)^(r&7).
// C/D: col=lane&31, row=(reg&3)+8*(reg>>2)+4*hl. Accum order ks0..ks3
// unchanged -> bit-identical to R2.
// ---------------------------------------------------------------------------
#define SB0() __builtin_amdgcn_sched_barrier(0)
#define LGKM(n) asm volatile("s_waitcnt lgkmcnt(" #n ")" ::: "memory")
#define VMCW(n) asm volatile("s_waitcnt vmcnt(" #n ")" ::: "memory")
#define BAR() asm volatile("s_barrier" ::: "memory")

#define STAGE1(Sbase, dsto, gp, uoff)                                          \
  __builtin_amdgcn_global_load_lds(                                            \
      (const __attribute__((address_space(1))) void*)((gp) + (uoff) + pl),     \
      (__attribute__((address_space(3))) void*)((Sbase) + (dsto) + ldst), 16, 0, 0)

#define STAGE_A(h, dsto, gk)                                                   \
  STAGE1(As, (dsto), A, uA + ((h)*128) * 2048 + (gk));                         \
  STAGE1(As, (dsto) + 4096, A, uA + ((h)*128 + 64) * 2048 + (gk))

#define STAGE_B(h, dsto, gk)                                                   \
  STAGE1(Bs, (dsto), B, uB + ((h)*128) * 2048 + (gk));                         \
  STAGE1(Bs, (dsto) + 4096, B, uB + ((h)*128 + 64) * 2048 + (gk))

// read the 6 frags (4 A + 2 B) of one k-slice into a register set
#define READ_KS(aS, bS, ks, base)                                              \
  _Pragma("unroll") for (int ah_ = 0; ah_ < 2; ah_++)                          \
      _Pragma("unroll") for (int m_ = 0; m_ < 2; m_++)                         \
          aS[ah_][m_] = *(const bf16x8*)(As + (base) + ah_ * 8192 + rbA +      \
                                         m_ * 2048 + ((((ks)*2 + hl) ^ key) * 8)); \
  _Pragma("unroll") for (int bh_ = 0; bh_ < 2; bh_++)                          \
      bS[bh_] = *(const bf16x8*)(Bs + (base) + bh_ * 8192 + rbB +              \
                                 ((((ks)*2 + hl) ^ key) * 8))

// 8 independent MFMAs: all (ah, bh, m) fragments at one k-slice
#define MFMA_KS(aS, bS)                                                        \
  acc[0][0][0] = __builtin_amdgcn_mfma_f32_32x32x16_bf16(aS[0][0], bS[0], acc[0][0][0], 0, 0, 0); \
  acc[1][0][0] = __builtin_amdgcn_mfma_f32_32x32x16_bf16(aS[1][0], bS[0], acc[1][0][0], 0, 0, 0); \
  acc[0][1][0] = __builtin_amdgcn_mfma_f32_32x32x16_bf16(aS[0][0], bS[1], acc[0][1][0], 0, 0, 0); \
  acc[1][1][0] = __builtin_amdgcn_mfma_f32_32x32x16_bf16(aS[1][0], bS[1], acc[1][1][0], 0, 0, 0); \
  acc[0][0][1] = __builtin_amdgcn_mfma_f32_32x32x16_bf16(aS[0][1], bS[0], acc[0][0][1], 0, 0, 0); \
  acc[1][0][1] = __builtin_amdgcn_mfma_f32_32x32x16_bf16(aS[1][1], bS[0], acc[1][0][1], 0, 0, 0); \
  acc[0][1][1] = __builtin_amdgcn_mfma_f32_32x32x16_bf16(aS[0][1], bS[1], acc[0][1][1], 0, 0, 0); \
  acc[1][1][1] = __builtin_amdgcn_mfma_f32_32x32x16_bf16(aS[1][1], bS[1], acc[1][1][1], 0, 0, 0)

__global__ __launch_bounds__(512, 2) void gemm_kernel(const u16* __restrict__ A,
                                                      const u16* __restrict__ B,
                                                      float* __restrict__ C) {
  __shared__ alignas(128) u16 As[4 * 8192];   // 64 KiB: 2 parity x 2 half
  __shared__ alignas(128) u16 Bs[4 * 8192];   // 64 KiB
  const int tid = threadIdx.x;
  const int lane = tid & 63;
  const int w = tid >> 6;        // wave 0..7
  const int wr = w >> 2;         // M split (0..1)
  const int wc = w & 3;          // N split (0..3)
  const int r32 = lane & 31;
  const int hl = lane >> 5;

  // T1: XCD x <- flat%8 gets by in [4x,4x+4), all 8 bx.
  const int F = blockIdx.x + (blockIdx.y << 3);
  const int li = F >> 3;
  const int m0 = ((F & 7) * 4 + (li >> 3)) << 8;
  const int n0 = (li & 7) << 8;

  // staging: lane l -> LDS linear l*16B (row l>>3, oct l&7); global octet
  // soct = (l&7)^(l>>3).
  const int srow = lane >> 3;
  const int soct = (lane & 7) ^ srow;
  const int uA = m0 * 2048;
  const int uB = n0 * 2048;
  const int pl = (w * 8 + srow) * 2048 + soct * 8;
  const int ldst = w * 512;           // u16: wave's 8 stage rows within slot

  const int key = r32 & 7;            // read-side swizzle key
  const int rbA = (wr * 64 + r32) * 64;
  const int rbB = (wc * 32 + r32) * 64;

  f32x16 acc[2][2][2] = {};
  bf16x8 a0_[2][2], b0_[2];   // even-ks register set
  bf16x8 a1_[2][2], b1_[2];   // odd-ks register set

  // Prologue: stage tile 0 (parity 0), drain, read ks0 -> S0 (drains at
  // p0's LGKM(6)).
  STAGE_A(0, 0, 0); STAGE_A(1, 8192, 0);
  STAGE_B(0, 0, 0); STAGE_B(1, 8192, 0);
  VMCW(0);
  BAR();
  SB0();
  READ_KS(a0_, b0_, 0, 0);
  SB0();

#pragma unroll 1
  for (int t = 0; t < 32; t++) {
    const int pav = (t & 1) << 14;    // current-parity slot base (u16)
    const int pnv = 16384 - pav;      // next-parity slot base
    const int k1 = (t < 31 ? t + 1 : 31) * 64;
    // ---- p0: stage tile t+1 (4 half-tiles) -> pnv; read ks1; MFMA ks0
    STAGE_A(0, pnv, k1); STAGE_A(1, pnv + 8192, k1);
    STAGE_B(0, pnv, k1); STAGE_B(1, pnv + 8192, k1);
    SB0();
    READ_KS(a1_, b1_, 1, pav);
    SB0();
    LGKM(6); SB0();                   // ks0 done (issued last phase); ks1 in flight
    __builtin_amdgcn_s_setprio(1);
    MFMA_KS(a0_, b0_);
    __builtin_amdgcn_s_setprio(0);
    SB0();
    // ---- p1: read ks2 -> S0; MFMA ks1
    READ_KS(a0_, b0_, 2, pav);
    SB0();
    LGKM(6); SB0();
    __builtin_amdgcn_s_setprio(1);
    MFMA_KS(a1_, b1_);
    __builtin_amdgcn_s_setprio(0);
    SB0();
    // ---- p2: read ks3 -> S1; MFMA ks2
    READ_KS(a1_, b1_, 3, pav);
    SB0();
    LGKM(6); SB0();
    __builtin_amdgcn_s_setprio(1);
    MFMA_KS(a0_, b0_);
    __builtin_amdgcn_s_setprio(0);
    SB0();
    // ---- p3: gate tile t+1 residency (exact drain: only its 8 stage instrs
    //      are in flight, issued 3 phases ago); read ks0(t+1) from pnv;
    //      MFMA ks3; closing barrier makes all waves' ks3 drains visible
    //      before anyone stages t+2 over tile-t slots at p0(t+1).
    VMCW(0);
    BAR();
    SB0();
    READ_KS(a0_, b0_, 0, pnv);
    SB0();
    LGKM(6); SB0();                   // ks3 done; ks0(t+1) in flight
    __builtin_amdgcn_s_setprio(1);
    MFMA_KS(a1_, b1_);
    __builtin_amdgcn_s_setprio(0);
    SB0();
    BAR();
    SB0();
  }

  // drain the tail's dead ks0 reads and any DMA before LDS dealloc
  LGKM(0);
  VMCW(0);

#pragma unroll
  for (int ah = 0; ah < 2; ah++)
#pragma unroll
    for (int bh = 0; bh < 2; bh++)
#pragma unroll
      for (int m = 0; m < 2; m++) {
        size_t cbase = (size_t)(m0 + ah * 128 + wr * 64 + m * 32 + 4 * hl) * 2048 +
                       (n0 + bh * 128 + wc * 32 + r32);
#pragma unroll
        for (int reg = 0; reg < 16; reg++) {
          int row = (reg & 3) + 8 * (reg >> 2);   // +4*hl folded into cbase
          __builtin_nontemporal_store(acc[ah][bh][m][reg], C + cbase + (size_t)row * 2048);
        }
      }
}

extern "C" void kernel_launch(void* const* d_in, const int* in_sizes, int n_in,
                              void* d_out, int out_size, void* d_ws, size_t ws_size,
                              hipStream_t stream) {
  const float* x = (const float*)d_in[0];
  const float* p0 = (const float*)d_in[1];
  const float* p1 = (const float*)d_in[2];
  const float* p2 = (const float*)d_in[3];
  const float* p3 = (const float*)d_in[4];
  const float* p4 = (const float*)d_in[5];
  const float* p5 = (const float*)d_in[6];
  const float* p6 = (const float*)d_in[7];
  const float* p7 = (const float*)d_in[8];
  const float* p8 = (const float*)d_in[9];
  char* ws = (char*)d_ws;
  // ws layout (bytes): xbf 33554432 | Wt 8388608 | L4 1048576 | R 16384
  u16* xbf = (u16*)ws;
  u16* Wt = (u16*)(ws + 33554432);
  float* L4 = (float*)(ws + 41943040);
  float* R = (float*)(ws + 42991616);

  build_lr_kernel<<<65, 256, 0, stream>>>(p0, p1, p2, p3, p4, p5, p6, p7, p8, L4, R);
  prep_kernel<<<10240, 256, 0, stream>>>(L4, R, Wt, x, xbf);
  gemm_kernel<<<dim3(8, 32), 512, 0, stream>>>(xbf, Wt, (float*)d_out);
}